// Round 17
// baseline (159.409 us; speedup 1.0000x reference)
//
#include <hip/hip_runtime.h>
#include <hip/hip_cooperative_groups.h>
#include <cstdint>
#include <cstddef>

namespace cg = cooperative_groups;

// Dims (fixed by the reference)
#define R_   16
#define NH_  8
#define D_   32
#define C_   256
#define B_   16
#define XY_  1024      // 32*32
#define RH_  128       // R_*NH_
#define KD_  4096      // R_*NH_*D_
#define NT   32        // positions per block (main)
#define PST  32        // partial LDS row stride (floats; 2-way bank = free)

#define LD4(p) (*reinterpret_cast<const float4*>(p))

using short8 = __attribute__((ext_vector_type(8))) short;   // 8 bf16 (4 VGPR)
using f32x16 = __attribute__((ext_vector_type(16))) float;  // MFMA 32x32 acc

__device__ __forceinline__ short bf16rn(float x) {
    unsigned u = __float_as_uint(x);
    u = (u + 0x7FFFu + ((u >> 16) & 1u)) >> 16;
    return (short)u;
}
__device__ __forceinline__ float bf16tof(short h) {
    return __uint_as_float(((unsigned)(unsigned short)h) << 16);
}

// ===========================================================================
// FUSED cooperative kernel: 512 blocks x 512 thr, 2 blocks/CU (64 KB LDS,
// VGPR capped 128 by launch_bounds). One launch, zero inter-kernel gap.
//   Part A (all blocks): build z B-frags into own LDS.
//   Part A' (bid<256):   precompute+pack weights (kv aliased onto P0);
//                        co-located light blocks keep every CU busy.
//   threadfence + grid.sync()  (device fence: weights visible cross-XCD)
//   Part B: phases 1-3 of R16 (GEMM1 split-K -> softmax fused scatter ->
//           GEMM2), verified layouts unchanged.
// ===========================================================================
__global__ __launch_bounds__(512, 4)
void rims_fused(const float* __restrict__ z,
                const float* __restrict__ rims,
                const float* __restrict__ Wk,  const float* __restrict__ bk,
                const float* __restrict__ Wv,  const float* __restrict__ bv,
                const float* __restrict__ Wq,  const float* __restrict__ bq,
                const float* __restrict__ Wm,  const float* __restrict__ bm,
                short* __restrict__ WLf_hi, short* __restrict__ WLf_lo,
                short* __restrict__ Uf_hi,  short* __restrict__ Uf_lo,
                float* __restrict__ c0o,
                float* __restrict__ out)
{
    __shared__ short8 Bf[32 * 64];       // 32 KB
    __shared__ float  P0[RH_ * PST];     // 16 KB (aliased as kv[] in part A')
    __shared__ float  P1[RH_ * PST];     // 16 KB

    const int tid = threadIdx.x;
    const int l   = tid & 63;
    const int w   = tid >> 6;            // 0..7
    const int g   = l >> 5;
    const int n31 = l & 31;
    const int bid = blockIdx.x;
    const int b   = bid >> 5;
    const int xy0 = (bid & 31) * NT;
    const float* zb = z + (size_t)b * C_ * XY_ + xy0;

    // ---- Part A: z B-frags (ALL blocks; 2 frag-pairs per wave) ----
    #pragma unroll
    for (int i = 0; i < 2; ++i) {
        const int kt = w * 2 + i;        // 0..15
        float x[8];
        short8 hi, lo;
        #pragma unroll
        for (int e = 0; e < 8; ++e)
            x[e] = zb[(size_t)(kt * 16 + 8 * g + e) * XY_ + n31];
        #pragma unroll
        for (int e = 0; e < 8; ++e) {
            const short hh = bf16rn(x[e]);
            hi[e] = hh;
            lo[e] = bf16rn(x[e] - bf16tof(hh));
        }
        Bf[(kt * 2 + 0) * 64 + l] = hi;
        Bf[(kt * 2 + 1) * 64 + l] = lo;
    }

    // ---- Part A': precompute + pack (bid < 256) ----
    if (bid < 256) {
        const int rh   = bid >> 1;
        const int half = bid & 1;
        const int rr   = rh >> 3;
        const int h    = rh & 7;
        const int c    = tid >> 1;       // 0..255
        const int dh   = tid & 1;        // d-half selector
        float* kv = P0;                  // alias: P0 unused until phase 1

        // prefetch fold weights (latency overlaps dots)
        float fw[16];
        if (half == 0) {
            const float* wqp = Wq + ((size_t)rh * D_ + dh * 16) * C_ + c;
            #pragma unroll
            for (int i = 0; i < 16; ++i)
                fw[i] = wqp[(size_t)i * C_];
        } else {
            const float* wmp = Wm + (size_t)c * KD_ + rh * D_ + dh * 16;
            #pragma unroll
            for (int i4 = 0; i4 < 16; i4 += 4) {
                const float4 m4 = LD4(wmp + i4);
                fw[i4 + 0] = m4.x; fw[i4 + 1] = m4.y;
                fw[i4 + 2] = m4.z; fw[i4 + 3] = m4.w;
            }
        }

        // k/v dots: 32 dots x 16 lanes, line-coalesced
        {
            const int d    = tid >> 4;   // 0..31
            const int part = tid & 15;   // 0..15
            const float* Wsrc = (half ? Wv : Wk)
                              + ((size_t)rr * 256 + h * D_ + d) * C_ + part * 4;
            const float* rp   = rims + rr * C_ + part * 4;
            float a0 = 0.f, a1 = 0.f, a2 = 0.f, a3 = 0.f;
            #pragma unroll
            for (int j = 0; j < 4; ++j) {
                const float4 w4 = LD4(Wsrc + j * 64);
                const float4 x4 = LD4(rp + j * 64);
                a0 = fmaf(w4.x, x4.x, a0); a1 = fmaf(w4.y, x4.y, a1);
                a2 = fmaf(w4.z, x4.z, a2); a3 = fmaf(w4.w, x4.w, a3);
            }
            float acc = (a0 + a1) + (a2 + a3);
            acc += __shfl_xor(acc, 1);
            acc += __shfl_xor(acc, 2);
            acc += __shfl_xor(acc, 4);
            acc += __shfl_xor(acc, 8);
            if (part == 0)
                kv[d] = acc + (half ? bv : bk)[rr * 256 + h * D_ + d];
        }
        __syncthreads();

        // fold (split over lane pair) + hi/lo split + fragment write
        {
            float x = 0.f;
            #pragma unroll
            for (int i = 0; i < 16; ++i)
                x = fmaf(kv[dh * 16 + i], fw[i], x);
            x += __shfl_xor(x, 1);       // combine d-halves

            if (half == 0) {
                const size_t off =
                    ((size_t)((c >> 4) * 4 + (rh >> 5)) * 64
                     + ((c >> 3) & 1) * 32 + (rh & 31)) * 8 + (c & 7);
                const short hi = bf16rn(x);
                if (dh == 0) WLf_hi[off] = hi;
                else         WLf_lo[off] = bf16rn(x - bf16tof(hi));
            } else {
                x += 0.125f * bm[c];     // bm folded: sum_rh attn == NH_ == 8
                const size_t off =
                    ((size_t)((rh >> 4) * 8 + (c >> 5)) * 64
                     + ((rh >> 3) & 1) * 32 + (c & 31)) * 8 + (rh & 7);
                const short hi = bf16rn(x);
                if (dh == 0) Uf_hi[off] = hi;
                else         Uf_lo[off] = bf16rn(x - bf16tof(hi));
            }
        }

        // c0[rh] = k · bq slice
        if (half == 0 && tid < D_) {
            float s = kv[tid] * bq[rh * D_ + tid];
            s += __shfl_xor(s, 1);  s += __shfl_xor(s, 2);  s += __shfl_xor(s, 4);
            s += __shfl_xor(s, 8);  s += __shfl_xor(s, 16);
            if (tid == 0) c0o[rh] = s;
        }
    }

    __threadfence();                     // device-scope: weights visible
    cg::this_grid().sync();              // also a block barrier (Bf ready)

    const int mt1 = w & 3, ks = w >> 2;
    const int kt0 = ks * 8;

    // prefetch first GEMM1 A-frag pair
    const short8 w0h = *reinterpret_cast<const short8*>(
        WLf_hi + ((size_t)(kt0 * 4 + mt1) * 64 + l) * 8);
    const short8 w0l = *reinterpret_cast<const short8*>(
        WLf_lo + ((size_t)(kt0 * 4 + mt1) * 64 + l) * 8);

    // ---- Phase 1: GEMM1 split-K (M=128 rh, N=32, K=256) ----
    {
        f32x16 aA, aB;
        #pragma unroll
        for (int i = 0; i < 16; ++i) { aA[i] = 0.f; aB[i] = 0.f; }

        {
            const short8 bhi = Bf[(kt0 * 2 + 0) * 64 + l];
            const short8 blo = Bf[(kt0 * 2 + 1) * 64 + l];
            aA = __builtin_amdgcn_mfma_f32_32x32x16_bf16(w0h, bhi, aA, 0, 0, 0);
            aB = __builtin_amdgcn_mfma_f32_32x32x16_bf16(w0h, blo, aB, 0, 0, 0);
            aB = __builtin_amdgcn_mfma_f32_32x32x16_bf16(w0l, bhi, aB, 0, 0, 0);
        }
        #pragma unroll 2
        for (int k8 = 1; k8 < 8; ++k8) {
            const int kt = kt0 + k8;
            const short8 bhi = Bf[(kt * 2 + 0) * 64 + l];
            const short8 blo = Bf[(kt * 2 + 1) * 64 + l];
            const short8 ahi = *reinterpret_cast<const short8*>(
                WLf_hi + ((size_t)(kt * 4 + mt1) * 64 + l) * 8);
            const short8 alo = *reinterpret_cast<const short8*>(
                WLf_lo + ((size_t)(kt * 4 + mt1) * 64 + l) * 8);
            aA = __builtin_amdgcn_mfma_f32_32x32x16_bf16(ahi, bhi, aA, 0, 0, 0);
            aB = __builtin_amdgcn_mfma_f32_32x32x16_bf16(ahi, blo, aB, 0, 0, 0);
            aB = __builtin_amdgcn_mfma_f32_32x32x16_bf16(alo, bhi, aB, 0, 0, 0);
        }
        const f32x16 acc = aA + aB;
        if (ks == 0) {
            #pragma unroll
            for (int r = 0; r < 16; ++r) {
                const int row = (r & 3) + 8 * (r >> 2) + 4 * g;
                const int rg  = mt1 * 32 + row;
                P0[rg * PST + n31] = acc[r] + c0o[rg];   // c0 folded here
            }
        } else {
            #pragma unroll
            for (int r = 0; r < 16; ++r) {
                const int row = (r & 3) + 8 * (r >> 2) + 4 * g;
                P1[(mt1 * 32 + row) * PST + n31] = acc[r];
            }
        }
    }
    __syncthreads();

    // ---- Phase 2 (fused): softmax + direct attn-fragment scatter ----
    if (tid < 256) {
        const int h = tid >> 5;          // 0..7
        const int p = tid & 31;
        float v[R_];
        float mx = -1e30f;
        #pragma unroll
        for (int r = 0; r < R_; ++r) {
            const int row = r * NH_ + h;
            v[r] = P0[row * PST + p] + P1[row * PST + p];
            mx = fmaxf(mx, v[r]);
        }
        float s = 0.f;
        #pragma unroll
        for (int r = 0; r < R_; ++r) { v[r] = __expf(v[r] - mx); s += v[r]; }
        const float inv = 1.f / s;

        short* bfs = reinterpret_cast<short*>(Bf);
        #pragma unroll
        for (int r = 0; r < R_; ++r) {
            const float a  = v[r] * inv;
            const short hi = bf16rn(a);
            const short lo = bf16rn(a - bf16tof(hi));
            const int kt   = r >> 1;
            const int lane = (r & 1) * 32 + p;
            bfs[((kt * 2 + 0) * 64 + lane) * 8 + h] = hi;
            bfs[((kt * 2 + 1) * 64 + lane) * 8 + h] = lo;
        }
    }

    // prefetch first GEMM2 A-frag pair (overlaps softmax)
    const short8 u0h = *reinterpret_cast<const short8*>(
        Uf_hi + ((size_t)w * 64 + l) * 8);
    const short8 u0l = *reinterpret_cast<const short8*>(
        Uf_lo + ((size_t)w * 64 + l) * 8);
    __syncthreads();

    // ---- Phase 3: GEMM2 (M=256 c, N=32, K=128) + store ----
    {
        const int mt = w;
        f32x16 p, q;
        #pragma unroll
        for (int i = 0; i < 16; ++i) { p[i] = 0.f; q[i] = 0.f; }

        {
            const short8 bhi = Bf[0 * 64 + l];
            const short8 blo = Bf[1 * 64 + l];
            p = __builtin_amdgcn_mfma_f32_32x32x16_bf16(u0h, bhi, p, 0, 0, 0);
            q = __builtin_amdgcn_mfma_f32_32x32x16_bf16(u0h, blo, q, 0, 0, 0);
            q = __builtin_amdgcn_mfma_f32_32x32x16_bf16(u0l, bhi, q, 0, 0, 0);
        }
        #pragma unroll 2
        for (int kt = 1; kt < 8; ++kt) {
            const short8 bhi = Bf[(kt * 2 + 0) * 64 + l];
            const short8 blo = Bf[(kt * 2 + 1) * 64 + l];
            const short8 ahi = *reinterpret_cast<const short8*>(
                Uf_hi + ((size_t)(kt * 8 + mt) * 64 + l) * 8);
            const short8 alo = *reinterpret_cast<const short8*>(
                Uf_lo + ((size_t)(kt * 8 + mt) * 64 + l) * 8);
            p = __builtin_amdgcn_mfma_f32_32x32x16_bf16(ahi, bhi, p, 0, 0, 0);
            q = __builtin_amdgcn_mfma_f32_32x32x16_bf16(ahi, blo, q, 0, 0, 0);
            q = __builtin_amdgcn_mfma_f32_32x32x16_bf16(alo, bhi, q, 0, 0, 0);
        }
        const f32x16 o = p + q;

        float* ob = out + (size_t)b * C_ * XY_ + xy0 + n31;
        #pragma unroll
        for (int r = 0; r < 16; ++r) {
            const int row = (r & 3) + 8 * (r >> 2) + 4 * g;
            ob[(size_t)(mt * 32 + row) * XY_] = o[r];
        }
    }
}

// ===========================================================================
// Fallback path (R16, proven 22.1 us): used if cooperative launch fails.
// ===========================================================================
__global__ __launch_bounds__(512)
void rims_precompute(const float* __restrict__ rims,
                     const float* __restrict__ Wk,
                     const float* __restrict__ bk,
                     const float* __restrict__ Wv,
                     const float* __restrict__ bv,
                     const float* __restrict__ Wq,
                     const float* __restrict__ bq,
                     const float* __restrict__ Wm,
                     const float* __restrict__ bm,
                     short* __restrict__ WLf_hi, short* __restrict__ WLf_lo,
                     short* __restrict__ Uf_hi,  short* __restrict__ Uf_lo,
                     float* __restrict__ c0o)
{
    const int bid  = blockIdx.x;
    const int rh   = bid >> 1;
    const int half = bid & 1;
    const int r    = rh >> 3;
    const int h    = rh & 7;
    const int tid  = threadIdx.x;
    const int c    = tid >> 1;
    const int dh   = tid & 1;

    __shared__ float kv[D_];

    float fw[16];
    if (half == 0) {
        const float* wqp = Wq + ((size_t)rh * D_ + dh * 16) * C_ + c;
        #pragma unroll
        for (int i = 0; i < 16; ++i)
            fw[i] = wqp[(size_t)i * C_];
    } else {
        const float* wmp = Wm + (size_t)c * KD_ + rh * D_ + dh * 16;
        #pragma unroll
        for (int i4 = 0; i4 < 16; i4 += 4) {
            const float4 m4 = LD4(wmp + i4);
            fw[i4 + 0] = m4.x; fw[i4 + 1] = m4.y;
            fw[i4 + 2] = m4.z; fw[i4 + 3] = m4.w;
        }
    }

    {
        const int d    = tid >> 4;
        const int part = tid & 15;
        const float* Wsrc = (half ? Wv : Wk)
                          + ((size_t)r * 256 + h * D_ + d) * C_ + part * 4;
        const float* rr   = rims + r * C_ + part * 4;
        float a0 = 0.f, a1 = 0.f, a2 = 0.f, a3 = 0.f;
        #pragma unroll
        for (int j = 0; j < 4; ++j) {
            const float4 w4 = LD4(Wsrc + j * 64);
            const float4 x4 = LD4(rr + j * 64);
            a0 = fmaf(w4.x, x4.x, a0); a1 = fmaf(w4.y, x4.y, a1);
            a2 = fmaf(w4.z, x4.z, a2); a3 = fmaf(w4.w, x4.w, a3);
        }
        float acc = (a0 + a1) + (a2 + a3);
        acc += __shfl_xor(acc, 1);
        acc += __shfl_xor(acc, 2);
        acc += __shfl_xor(acc, 4);
        acc += __shfl_xor(acc, 8);
        if (part == 0)
            kv[d] = acc + (half ? bv : bk)[r * 256 + h * D_ + d];
    }
    __syncthreads();

    {
        float x = 0.f;
        #pragma unroll
        for (int i = 0; i < 16; ++i)
            x = fmaf(kv[dh * 16 + i], fw[i], x);
        x += __shfl_xor(x, 1);

        if (half == 0) {
            const size_t off =
                ((size_t)((c >> 4) * 4 + (rh >> 5)) * 64
                 + ((c >> 3) & 1) * 32 + (rh & 31)) * 8 + (c & 7);
            const short hi = bf16rn(x);
            if (dh == 0) WLf_hi[off] = hi;
            else         WLf_lo[off] = bf16rn(x - bf16tof(hi));
        } else {
            x += 0.125f * bm[c];
            const size_t off =
                ((size_t)((rh >> 4) * 8 + (c >> 5)) * 64
                 + ((rh >> 3) & 1) * 32 + (c & 31)) * 8 + (rh & 7);
            const short hi = bf16rn(x);
            if (dh == 0) Uf_hi[off] = hi;
            else         Uf_lo[off] = bf16rn(x - bf16tof(hi));
        }
    }

    if (half == 0 && tid < D_) {
        float s = kv[tid] * bq[rh * D_ + tid];
        s += __shfl_xor(s, 1);  s += __shfl_xor(s, 2);  s += __shfl_xor(s, 4);
        s += __shfl_xor(s, 8);  s += __shfl_xor(s, 16);
        if (tid == 0) c0o[rh] = s;
    }
}

__global__ __launch_bounds__(512, 4)
void rims_mfma(const float* __restrict__ z,
               const short* __restrict__ WLf_hi, const short* __restrict__ WLf_lo,
               const short* __restrict__ Uf_hi,  const short* __restrict__ Uf_lo,
               const float* __restrict__ c0v,
               float* __restrict__ out)
{
    __shared__ short8 Bf[32 * 64];
    __shared__ float  P0[RH_ * PST];
    __shared__ float  P1[RH_ * PST];

    const int tid = threadIdx.x;
    const int l   = tid & 63;
    const int w   = tid >> 6;
    const int g   = l >> 5;
    const int n31 = l & 31;
    const int b   = blockIdx.x >> 5;
    const int xy0 = (blockIdx.x & 31) * NT;
    const float* zb = z + (size_t)b * C_ * XY_ + xy0;

    const int mt1 = w & 3, ks = w >> 2;
    const int kt0 = ks * 8;

    #pragma unroll
    for (int i = 0; i < 2; ++i) {
        const int kt = w * 2 + i;
        float x[8];
        short8 hi, lo;
        #pragma unroll
        for (int e = 0; e < 8; ++e)
            x[e] = zb[(size_t)(kt * 16 + 8 * g + e) * XY_ + n31];
        #pragma unroll
        for (int e = 0; e < 8; ++e) {
            const short hh = bf16rn(x[e]);
            hi[e] = hh;
            lo[e] = bf16rn(x[e] - bf16tof(hh));
        }
        Bf[(kt * 2 + 0) * 64 + l] = hi;
        Bf[(kt * 2 + 1) * 64 + l] = lo;
    }

    const short8 w0h = *reinterpret_cast<const short8*>(
        WLf_hi + ((size_t)(kt0 * 4 + mt1) * 64 + l) * 8);
    const short8 w0l = *reinterpret_cast<const short8*>(
        WLf_lo + ((size_t)(kt0 * 4 + mt1) * 64 + l) * 8);
    __syncthreads();

    {
        f32x16 aA, aB;
        #pragma unroll
        for (int i = 0; i < 16; ++i) { aA[i] = 0.f; aB[i] = 0.f; }

        {
            const short8 bhi = Bf[(kt0 * 2 + 0) * 64 + l];
            const short8 blo = Bf[(kt0 * 2 + 1) * 64 + l];
            aA = __builtin_amdgcn_mfma_f32_32x32x16_bf16(w0h, bhi, aA, 0, 0, 0);
            aB = __builtin_amdgcn_mfma_f32_32x32x16_bf16(w0h, blo, aB, 0, 0, 0);
            aB = __builtin_amdgcn_mfma_f32_32x32x16_bf16(w0l, bhi, aB, 0, 0, 0);
        }
        #pragma unroll 2
        for (int k8 = 1; k8 < 8; ++k8) {
            const int kt = kt0 + k8;
            const short8 bhi = Bf[(kt * 2 + 0) * 64 + l];
            const short8 blo = Bf[(kt * 2 + 1) * 64 + l];
            const short8 ahi = *reinterpret_cast<const short8*>(
                WLf_hi + ((size_t)(kt * 4 + mt1) * 64 + l) * 8);
            const short8 alo = *reinterpret_cast<const short8*>(
                WLf_lo + ((size_t)(kt * 4 + mt1) * 64 + l) * 8);
            aA = __builtin_amdgcn_mfma_f32_32x32x16_bf16(ahi, bhi, aA, 0, 0, 0);
            aB = __builtin_amdgcn_mfma_f32_32x32x16_bf16(ahi, blo, aB, 0, 0, 0);
            aB = __builtin_amdgcn_mfma_f32_32x32x16_bf16(alo, bhi, aB, 0, 0, 0);
        }
        const f32x16 acc = aA + aB;
        if (ks == 0) {
            #pragma unroll
            for (int r = 0; r < 16; ++r) {
                const int row = (r & 3) + 8 * (r >> 2) + 4 * g;
                const int rg  = mt1 * 32 + row;
                P0[rg * PST + n31] = acc[r] + c0v[rg];
            }
        } else {
            #pragma unroll
            for (int r = 0; r < 16; ++r) {
                const int row = (r & 3) + 8 * (r >> 2) + 4 * g;
                P1[(mt1 * 32 + row) * PST + n31] = acc[r];
            }
        }
    }
    __syncthreads();

    if (tid < 256) {
        const int h = tid >> 5;
        const int p = tid & 31;
        float v[R_];
        float mx = -1e30f;
        #pragma unroll
        for (int r = 0; r < R_; ++r) {
            const int row = r * NH_ + h;
            v[r] = P0[row * PST + p] + P1[row * PST + p];
            mx = fmaxf(mx, v[r]);
        }
        float s = 0.f;
        #pragma unroll
        for (int r = 0; r < R_; ++r) { v[r] = __expf(v[r] - mx); s += v[r]; }
        const float inv = 1.f / s;

        short* bfs = reinterpret_cast<short*>(Bf);
        #pragma unroll
        for (int r = 0; r < R_; ++r) {
            const float a  = v[r] * inv;
            const short hi = bf16rn(a);
            const short lo = bf16rn(a - bf16tof(hi));
            const int kt   = r >> 1;
            const int lane = (r & 1) * 32 + p;
            bfs[((kt * 2 + 0) * 64 + lane) * 8 + h] = hi;
            bfs[((kt * 2 + 1) * 64 + lane) * 8 + h] = lo;
        }
    }

    const short8 u0h = *reinterpret_cast<const short8*>(
        Uf_hi + ((size_t)w * 64 + l) * 8);
    const short8 u0l = *reinterpret_cast<const short8*>(
        Uf_lo + ((size_t)w * 64 + l) * 8);
    __syncthreads();

    {
        const int mt = w;
        f32x16 p, q;
        #pragma unroll
        for (int i = 0; i < 16; ++i) { p[i] = 0.f; q[i] = 0.f; }

        {
            const short8 bhi = Bf[0 * 64 + l];
            const short8 blo = Bf[1 * 64 + l];
            p = __builtin_amdgcn_mfma_f32_32x32x16_bf16(u0h, bhi, p, 0, 0, 0);
            q = __builtin_amdgcn_mfma_f32_32x32x16_bf16(u0h, blo, q, 0, 0, 0);
            q = __builtin_amdgcn_mfma_f32_32x32x16_bf16(u0l, bhi, q, 0, 0, 0);
        }
        #pragma unroll 2
        for (int kt = 1; kt < 8; ++kt) {
            const short8 bhi = Bf[(kt * 2 + 0) * 64 + l];
            const short8 blo = Bf[(kt * 2 + 1) * 64 + l];
            const short8 ahi = *reinterpret_cast<const short8*>(
                Uf_hi + ((size_t)(kt * 8 + mt) * 64 + l) * 8);
            const short8 alo = *reinterpret_cast<const short8*>(
                Uf_lo + ((size_t)(kt * 8 + mt) * 64 + l) * 8);
            p = __builtin_amdgcn_mfma_f32_32x32x16_bf16(ahi, bhi, p, 0, 0, 0);
            q = __builtin_amdgcn_mfma_f32_32x32x16_bf16(ahi, blo, q, 0, 0, 0);
            q = __builtin_amdgcn_mfma_f32_32x32x16_bf16(alo, bhi, q, 0, 0, 0);
        }
        const f32x16 o = p + q;

        float* ob = out + (size_t)b * C_ * XY_ + xy0 + n31;
        #pragma unroll
        for (int r = 0; r < 16; ++r) {
            const int row = (r & 3) + 8 * (r >> 2) + 4 * g;
            ob[(size_t)(mt * 32 + row) * XY_] = o[r];
        }
    }
}

// ---------------------------------------------------------------------------
extern "C" void kernel_launch(void* const* d_in, const int* in_sizes, int n_in,
                              void* d_out, int out_size, void* d_ws, size_t ws_size,
                              hipStream_t stream)
{
    const float* z    = (const float*)d_in[0];
    const float* rims = (const float*)d_in[1];
    const float* Wk   = (const float*)d_in[2];
    const float* bk   = (const float*)d_in[3];
    const float* Wv   = (const float*)d_in[4];
    const float* bv   = (const float*)d_in[5];
    const float* Wq   = (const float*)d_in[6];
    const float* bq   = (const float*)d_in[7];
    const float* Wm   = (const float*)d_in[8];
    const float* bm   = (const float*)d_in[9];
    float* out = (float*)d_out;

    // ws: WLf_hi/lo (32768 shorts each) | Uf_hi/lo | c0 (256 f)
    short* WLf_hi = (short*)d_ws;
    short* WLf_lo = WLf_hi + 32768;
    short* Uf_hi  = WLf_lo + 32768;
    short* Uf_lo  = Uf_hi + 32768;
    float* c0o    = (float*)(Uf_lo + 32768);

    void* args[] = {
        (void*)&z, (void*)&rims, (void*)&Wk, (void*)&bk, (void*)&Wv, (void*)&bv,
        (void*)&Wq, (void*)&bq, (void*)&Wm, (void*)&bm,
        (void*)&WLf_hi, (void*)&WLf_lo, (void*)&Uf_hi, (void*)&Uf_lo,
        (void*)&c0o, (void*)&out
    };
    const hipError_t err = hipLaunchCooperativeKernel(
        (const void*)rims_fused, dim3(B_ * XY_ / NT), dim3(512),
        (void**)args, 0, stream);

    if (err != hipSuccess) {
        // deterministic fallback: proven two-kernel path
        rims_precompute<<<2 * RH_, 512, 0, stream>>>(rims, Wk, bk, Wv, bv, Wq, bq,
                                                     Wm, bm, WLf_hi, WLf_lo,
                                                     Uf_hi, Uf_lo, c0o);
        rims_mfma<<<(B_ * XY_) / NT, 512, 0, stream>>>(z, WLf_hi, WLf_lo,
                                                       Uf_hi, Uf_lo, c0o, out);
    }
}

// Round 18
// 40.807 us; speedup vs baseline: 3.9064x; 3.9064x over previous
//
#include <hip/hip_runtime.h>
#include <cstdint>
#include <cstddef>

// Dims (fixed by the reference)
#define R_   16
#define NH_  8
#define D_   32
#define C_   256
#define B_   16
#define XY_  1024      // 32*32
#define RH_  128       // R_*NH_
#define KD_  4096      // R_*NH_*D_
#define NT   32        // positions per block (main kernel)
#define PST  32        // partial LDS row stride (floats; 2-way bank = free)

#define LD4(p) (*reinterpret_cast<const float4*>(p))

using short8 = __attribute__((ext_vector_type(8))) short;   // 8 bf16 (4 VGPR)
using f32x16 = __attribute__((ext_vector_type(16))) float;  // MFMA 32x32 acc

__device__ __forceinline__ short bf16rn(float x) {
    unsigned u = __float_as_uint(x);
    u = (u + 0x7FFFu + ((u >> 16) & 1u)) >> 16;
    return (short)u;
}
__device__ __forceinline__ float bf16tof(short h) {
    return __uint_as_float(((unsigned)(unsigned short)h) << 16);
}

// ---------------------------------------------------------------------------
// Precompute + pack fused (identical to R16, the 22.1us best).
// 256 blocks (bid = rh*2 + half) x 512 thr.
// Fragment convention (32x32x16, A and B share it): lane l -> non-K = l&31,
// K-slot e -> k = kt*16 + 8*(l>>5) + e.
// ---------------------------------------------------------------------------
__global__ __launch_bounds__(512)
void rims_precompute(const float* __restrict__ rims,
                     const float* __restrict__ Wk,
                     const float* __restrict__ bk,
                     const float* __restrict__ Wv,
                     const float* __restrict__ bv,
                     const float* __restrict__ Wq,
                     const float* __restrict__ bq,
                     const float* __restrict__ Wm,
                     const float* __restrict__ bm,
                     short* __restrict__ WLf_hi, short* __restrict__ WLf_lo,
                     short* __restrict__ Uf_hi,  short* __restrict__ Uf_lo,
                     float* __restrict__ c0o)
{
    const int bid  = blockIdx.x;       // 0..255
    const int rh   = bid >> 1;
    const int half = bid & 1;
    const int r    = rh >> 3;
    const int h    = rh & 7;
    const int tid  = threadIdx.x;      // 0..511
    const int c    = tid >> 1;         // 0..255
    const int dh   = tid & 1;          // d-half selector

    __shared__ float kv[D_];

    // ---- prefetch fold weights (latency overlaps dots) ----
    float fw[16];
    if (half == 0) {
        const float* wqp = Wq + ((size_t)rh * D_ + dh * 16) * C_ + c;
        #pragma unroll
        for (int i = 0; i < 16; ++i)
            fw[i] = wqp[(size_t)i * C_];
    } else {
        const float* wmp = Wm + (size_t)c * KD_ + rh * D_ + dh * 16;
        #pragma unroll
        for (int i4 = 0; i4 < 16; i4 += 4) {
            const float4 m4 = LD4(wmp + i4);
            fw[i4 + 0] = m4.x; fw[i4 + 1] = m4.y;
            fw[i4 + 2] = m4.z; fw[i4 + 3] = m4.w;
        }
    }

    // ---- k/v dots: 32 dots x 16 lanes, line-coalesced ----
    {
        const int d    = tid >> 4;     // 0..31
        const int part = tid & 15;     // 0..15
        const float* Wsrc = (half ? Wv : Wk)
                          + ((size_t)r * 256 + h * D_ + d) * C_ + part * 4;
        const float* rr   = rims + r * C_ + part * 4;
        float a0 = 0.f, a1 = 0.f, a2 = 0.f, a3 = 0.f;
        #pragma unroll
        for (int j = 0; j < 4; ++j) {
            const float4 w4 = LD4(Wsrc + j * 64);
            const float4 x4 = LD4(rr + j * 64);
            a0 = fmaf(w4.x, x4.x, a0); a1 = fmaf(w4.y, x4.y, a1);
            a2 = fmaf(w4.z, x4.z, a2); a3 = fmaf(w4.w, x4.w, a3);
        }
        float acc = (a0 + a1) + (a2 + a3);
        acc += __shfl_xor(acc, 1);
        acc += __shfl_xor(acc, 2);
        acc += __shfl_xor(acc, 4);
        acc += __shfl_xor(acc, 8);
        if (part == 0)
            kv[d] = acc + (half ? bv : bk)[r * 256 + h * D_ + d];
    }
    __syncthreads();

    // ---- fold (split over lane pair) + hi/lo split + fragment write ----
    {
        float x = 0.f;
        #pragma unroll
        for (int i = 0; i < 16; ++i)
            x = fmaf(kv[dh * 16 + i], fw[i], x);
        x += __shfl_xor(x, 1);         // combine d-halves

        if (half == 0) {
            // WLf tile (kt=c>>4, mt=rh>>5); lane=((c>>3)&1)*32+(rh&31); e=c&7
            const size_t off =
                ((size_t)((c >> 4) * 4 + (rh >> 5)) * 64
                 + ((c >> 3) & 1) * 32 + (rh & 31)) * 8 + (c & 7);
            const short hi = bf16rn(x);
            if (dh == 0) WLf_hi[off] = hi;
            else         WLf_lo[off] = bf16rn(x - bf16tof(hi));
        } else {
            x += 0.125f * bm[c];       // bm folded: sum_rh attn == NH_ == 8
            // Uf tile (kt=rh>>4, mt=c>>5); lane=((rh>>3)&1)*32+(c&31); e=rh&7
            const size_t off =
                ((size_t)((rh >> 4) * 8 + (c >> 5)) * 64
                 + ((rh >> 3) & 1) * 32 + (c & 31)) * 8 + (rh & 7);
            const short hi = bf16rn(x);
            if (dh == 0) Uf_hi[off] = hi;
            else         Uf_lo[off] = bf16rn(x - bf16tof(hi));
        }
    }

    // ---- c0[rh] = k · bq slice ----
    if (half == 0 && tid < D_) {
        float s = kv[tid] * bq[rh * D_ + tid];
        s += __shfl_xor(s, 1);  s += __shfl_xor(s, 2);  s += __shfl_xor(s, 4);
        s += __shfl_xor(s, 8);  s += __shfl_xor(s, 16);
        if (tid == 0) c0o[rh] = s;
    }
}

// ---------------------------------------------------------------------------
// MFMA main: 512 blocks x 512 thr (8 waves), 32 positions per block.
// R18 deltas vs R16 (structure/layouts unchanged, all verified maps kept):
//   * single f32x16 accumulator per MFMA chain (C-in chaining) -> VGPR -16
//   * P1 eliminated: phase 0 zeroes P0, both split-K waves atomicAdd
//     (ds_add_f32) their partials; ks=0 folds c0. LDS 64 -> 48 KB;
//     softmax LDS reads halved.
//   * __launch_bounds__(512, 6): VGPR cap 80 -> up to 3 blocks/CU
//     (48 KB x 3 = 144 <= 160 KB), smoothing scheduling skew.
//   Phase 0: z B-frags -> Bf; zero P0; prefetch GEMM1 kt0 A-frags
//   Phase 1: GEMM1 split-K (mt=w&3, ks=w>>2) -> atomicAdd P0 (+c0 on ks=0)
//   Phase 2 (fused): softmax + direct attn-fragment scatter into Bf;
//            prefetch GEMM2 kt0 A-frags
//   Phase 3: GEMM2 (mt=w, K=128) + store
// C/D map (verified m74/m101): row=(r&3)+8(r>>2)+4g.
// ---------------------------------------------------------------------------
__global__ __launch_bounds__(512, 6)
void rims_mfma(const float* __restrict__ z,
               const short* __restrict__ WLf_hi, const short* __restrict__ WLf_lo,
               const short* __restrict__ Uf_hi,  const short* __restrict__ Uf_lo,
               const float* __restrict__ c0v,
               float* __restrict__ out)
{
    __shared__ short8 Bf[32 * 64];       // 32 KB
    __shared__ float  P0[RH_ * PST];     // 16 KB

    const int tid = threadIdx.x;
    const int l   = tid & 63;
    const int w   = tid >> 6;            // 0..7
    const int g   = l >> 5;
    const int n31 = l & 31;
    const int b   = blockIdx.x >> 5;
    const int xy0 = (blockIdx.x & 31) * NT;
    const float* zb = z + (size_t)b * C_ * XY_ + xy0;

    const int mt1 = w & 3, ks = w >> 2;  // GEMM1 assignment
    const int kt0 = ks * 8;

    // ---- Phase 0: z B-frags (2 frag-pairs per wave) + zero P0 ----
    #pragma unroll
    for (int i = 0; i < 2; ++i) {
        const int kt = w * 2 + i;        // 0..15
        float x[8];
        short8 hi, lo;
        #pragma unroll
        for (int e = 0; e < 8; ++e)
            x[e] = zb[(size_t)(kt * 16 + 8 * g + e) * XY_ + n31];
        #pragma unroll
        for (int e = 0; e < 8; ++e) {
            const short hh = bf16rn(x[e]);
            hi[e] = hh;
            lo[e] = bf16rn(x[e] - bf16tof(hh));
        }
        Bf[(kt * 2 + 0) * 64 + l] = hi;
        Bf[(kt * 2 + 1) * 64 + l] = lo;
    }
    {   // zero P0: 4096 floats / 512 thr = 2 float4 each
        const float4 zz = make_float4(0.f, 0.f, 0.f, 0.f);
        *reinterpret_cast<float4*>(&P0[tid * 8 + 0]) = zz;
        *reinterpret_cast<float4*>(&P0[tid * 8 + 4]) = zz;
    }

    // prefetch first GEMM1 A-frag pair (global only -> legal before barrier)
    const short8 w0h = *reinterpret_cast<const short8*>(
        WLf_hi + ((size_t)(kt0 * 4 + mt1) * 64 + l) * 8);
    const short8 w0l = *reinterpret_cast<const short8*>(
        WLf_lo + ((size_t)(kt0 * 4 + mt1) * 64 + l) * 8);
    __syncthreads();

    // ---- Phase 1: GEMM1 split-K (M=128 rh, N=32, K=256) ----
    {
        f32x16 acc;
        #pragma unroll
        for (int i = 0; i < 16; ++i) acc[i] = 0.f;

        // peeled kt0 (A-frags already in registers)
        {
            const short8 bhi = Bf[(kt0 * 2 + 0) * 64 + l];
            const short8 blo = Bf[(kt0 * 2 + 1) * 64 + l];
            acc = __builtin_amdgcn_mfma_f32_32x32x16_bf16(w0h, bhi, acc, 0, 0, 0);
            acc = __builtin_amdgcn_mfma_f32_32x32x16_bf16(w0h, blo, acc, 0, 0, 0);
            acc = __builtin_amdgcn_mfma_f32_32x32x16_bf16(w0l, bhi, acc, 0, 0, 0);
        }
        #pragma unroll 2
        for (int k8 = 1; k8 < 8; ++k8) {
            const int kt = kt0 + k8;
            const short8 bhi = Bf[(kt * 2 + 0) * 64 + l];
            const short8 blo = Bf[(kt * 2 + 1) * 64 + l];
            const short8 ahi = *reinterpret_cast<const short8*>(
                WLf_hi + ((size_t)(kt * 4 + mt1) * 64 + l) * 8);
            const short8 alo = *reinterpret_cast<const short8*>(
                WLf_lo + ((size_t)(kt * 4 + mt1) * 64 + l) * 8);
            acc = __builtin_amdgcn_mfma_f32_32x32x16_bf16(ahi, bhi, acc, 0, 0, 0);
            acc = __builtin_amdgcn_mfma_f32_32x32x16_bf16(ahi, blo, acc, 0, 0, 0);
            acc = __builtin_amdgcn_mfma_f32_32x32x16_bf16(alo, bhi, acc, 0, 0, 0);
        }

        // split-K reduce via LDS float atomics (P0 zeroed in phase 0)
        if (ks == 0) {
            #pragma unroll
            for (int r = 0; r < 16; ++r) {
                const int row = (r & 3) + 8 * (r >> 2) + 4 * g;
                const int rg  = mt1 * 32 + row;
                atomicAdd(&P0[rg * PST + n31], acc[r] + c0v[rg]);
            }
        } else {
            #pragma unroll
            for (int r = 0; r < 16; ++r) {
                const int row = (r & 3) + 8 * (r >> 2) + 4 * g;
                atomicAdd(&P0[(mt1 * 32 + row) * PST + n31], acc[r]);
            }
        }
    }
    __syncthreads();

    // ---- Phase 2 (fused): softmax + direct attn-fragment scatter ----
    if (tid < 256) {
        const int h = tid >> 5;          // 0..7
        const int p = tid & 31;
        float v[R_];
        float mx = -1e30f;
        #pragma unroll
        for (int r = 0; r < R_; ++r) {
            v[r] = P0[(r * NH_ + h) * PST + p];
            mx = fmaxf(mx, v[r]);
        }
        float s = 0.f;
        #pragma unroll
        for (int r = 0; r < R_; ++r) { v[r] = __expf(v[r] - mx); s += v[r]; }
        const float inv = 1.f / s;

        short* bfs = reinterpret_cast<short*>(Bf);
        #pragma unroll
        for (int r = 0; r < R_; ++r) {
            const float a  = v[r] * inv;
            const short hi = bf16rn(a);
            const short lo = bf16rn(a - bf16tof(hi));
            const int kt   = r >> 1;
            const int lane = (r & 1) * 32 + p;
            bfs[((kt * 2 + 0) * 64 + lane) * 8 + h] = hi;
            bfs[((kt * 2 + 1) * 64 + lane) * 8 + h] = lo;
        }
    }

    // prefetch first GEMM2 A-frag pair (global only; overlaps softmax)
    const short8 u0h = *reinterpret_cast<const short8*>(
        Uf_hi + ((size_t)w * 64 + l) * 8);             // kt=0 -> idx = mt = w
    const short8 u0l = *reinterpret_cast<const short8*>(
        Uf_lo + ((size_t)w * 64 + l) * 8);
    __syncthreads();

    // ---- Phase 3: GEMM2 (M=256 c, N=32, K=128) + store ----
    {
        const int mt = w;                // c tile [32w, 32w+32)
        f32x16 o;
        #pragma unroll
        for (int i = 0; i < 16; ++i) o[i] = 0.f;

        // peeled kt=0
        {
            const short8 bhi = Bf[0 * 64 + l];
            const short8 blo = Bf[1 * 64 + l];
            o = __builtin_amdgcn_mfma_f32_32x32x16_bf16(u0h, bhi, o, 0, 0, 0);
            o = __builtin_amdgcn_mfma_f32_32x32x16_bf16(u0h, blo, o, 0, 0, 0);
            o = __builtin_amdgcn_mfma_f32_32x32x16_bf16(u0l, bhi, o, 0, 0, 0);
        }
        #pragma unroll 2
        for (int kt = 1; kt < 8; ++kt) {
            const short8 bhi = Bf[(kt * 2 + 0) * 64 + l];
            const short8 blo = Bf[(kt * 2 + 1) * 64 + l];
            const short8 ahi = *reinterpret_cast<const short8*>(
                Uf_hi + ((size_t)(kt * 8 + mt) * 64 + l) * 8);
            const short8 alo = *reinterpret_cast<const short8*>(
                Uf_lo + ((size_t)(kt * 8 + mt) * 64 + l) * 8);
            o = __builtin_amdgcn_mfma_f32_32x32x16_bf16(ahi, bhi, o, 0, 0, 0);
            o = __builtin_amdgcn_mfma_f32_32x32x16_bf16(ahi, blo, o, 0, 0, 0);
            o = __builtin_amdgcn_mfma_f32_32x32x16_bf16(alo, bhi, o, 0, 0, 0);
        }

        float* ob = out + (size_t)b * C_ * XY_ + xy0 + n31;
        #pragma unroll
        for (int r = 0; r < 16; ++r) {
            const int row = (r & 3) + 8 * (r >> 2) + 4 * g;
            ob[(size_t)(mt * 32 + row) * XY_] = o[r];
        }
    }
}

// ---------------------------------------------------------------------------
extern "C" void kernel_launch(void* const* d_in, const int* in_sizes, int n_in,
                              void* d_out, int out_size, void* d_ws, size_t ws_size,
                              hipStream_t stream)
{
    const float* z    = (const float*)d_in[0];
    const float* rims = (const float*)d_in[1];
    const float* Wk   = (const float*)d_in[2];
    const float* bk   = (const float*)d_in[3];
    const float* Wv   = (const float*)d_in[4];
    const float* bv   = (const float*)d_in[5];
    const float* Wq   = (const float*)d_in[6];
    const float* bq   = (const float*)d_in[7];
    const float* Wm   = (const float*)d_in[8];
    const float* bm   = (const float*)d_in[9];
    float* out = (float*)d_out;

    // ws: WLf_hi/lo (32768 shorts each) | Uf_hi/lo | c0 (256 f)
    short* WLf_hi = (short*)d_ws;
    short* WLf_lo = WLf_hi + 32768;
    short* Uf_hi  = WLf_lo + 32768;
    short* Uf_lo  = Uf_hi + 32768;
    float* c0o    = (float*)(Uf_lo + 32768);

    rims_precompute<<<2 * RH_, 512, 0, stream>>>(rims, Wk, bk, Wv, bv, Wq, bq,
                                                 Wm, bm, WLf_hi, WLf_lo,
                                                 Uf_hi, Uf_lo, c0o);
    rims_mfma<<<(B_ * XY_) / NT, 512, 0, stream>>>(z, WLf_hi, WLf_lo,
                                                   Uf_hi, Uf_lo, c0o, out);
}

// Round 19
// 21.762 us; speedup vs baseline: 7.3252x; 1.8752x over previous
//
#include <hip/hip_runtime.h>
#include <cstdint>
#include <cstddef>

// Dims (fixed by the reference)
#define R_   16
#define NH_  8
#define D_   32
#define C_   256
#define B_   16
#define XY_  1024      // 32*32
#define RH_  128       // R_*NH_
#define KD_  4096      // R_*NH_*D_
#define NT   32        // positions per block (main kernel)
#define PST  36        // partial LDS row stride (floats; see bank math below)

#define LD4(p) (*reinterpret_cast<const float4*>(p))

using short8 = __attribute__((ext_vector_type(8))) short;   // 8 bf16 (4 VGPR)
using f32x16 = __attribute__((ext_vector_type(16))) float;  // MFMA 32x32 acc

__device__ __forceinline__ short bf16rn(float x) {
    unsigned u = __float_as_uint(x);
    u = (u + 0x7FFFu + ((u >> 16) & 1u)) >> 16;
    return (short)u;
}
__device__ __forceinline__ float bf16tof(short h) {
    return __uint_as_float(((unsigned)(unsigned short)h) << 16);
}

// ---------------------------------------------------------------------------
// Precompute + pack fused (identical to R16, the 22.1us best).
// 256 blocks (bid = rh*2 + half) x 512 thr.
// Fragment convention (32x32x16, A and B share it): lane l -> non-K = l&31,
// K-slot e -> k = kt*16 + 8*(l>>5) + e.
// ---------------------------------------------------------------------------
__global__ __launch_bounds__(512)
void rims_precompute(const float* __restrict__ rims,
                     const float* __restrict__ Wk,
                     const float* __restrict__ bk,
                     const float* __restrict__ Wv,
                     const float* __restrict__ bv,
                     const float* __restrict__ Wq,
                     const float* __restrict__ bq,
                     const float* __restrict__ Wm,
                     const float* __restrict__ bm,
                     short* __restrict__ WLf_hi, short* __restrict__ WLf_lo,
                     short* __restrict__ Uf_hi,  short* __restrict__ Uf_lo,
                     float* __restrict__ c0o)
{
    const int bid  = blockIdx.x;       // 0..255
    const int rh   = bid >> 1;
    const int half = bid & 1;
    const int r    = rh >> 3;
    const int h    = rh & 7;
    const int tid  = threadIdx.x;      // 0..511
    const int c    = tid >> 1;         // 0..255
    const int dh   = tid & 1;          // d-half selector

    __shared__ float kv[D_];

    // ---- prefetch fold weights (latency overlaps dots) ----
    float fw[16];
    if (half == 0) {
        const float* wqp = Wq + ((size_t)rh * D_ + dh * 16) * C_ + c;
        #pragma unroll
        for (int i = 0; i < 16; ++i)
            fw[i] = wqp[(size_t)i * C_];
    } else {
        const float* wmp = Wm + (size_t)c * KD_ + rh * D_ + dh * 16;
        #pragma unroll
        for (int i4 = 0; i4 < 16; i4 += 4) {
            const float4 m4 = LD4(wmp + i4);
            fw[i4 + 0] = m4.x; fw[i4 + 1] = m4.y;
            fw[i4 + 2] = m4.z; fw[i4 + 3] = m4.w;
        }
    }

    // ---- k/v dots: 32 dots x 16 lanes, line-coalesced ----
    {
        const int d    = tid >> 4;     // 0..31
        const int part = tid & 15;     // 0..15
        const float* Wsrc = (half ? Wv : Wk)
                          + ((size_t)r * 256 + h * D_ + d) * C_ + part * 4;
        const float* rr   = rims + r * C_ + part * 4;
        float a0 = 0.f, a1 = 0.f, a2 = 0.f, a3 = 0.f;
        #pragma unroll
        for (int j = 0; j < 4; ++j) {
            const float4 w4 = LD4(Wsrc + j * 64);
            const float4 x4 = LD4(rr + j * 64);
            a0 = fmaf(w4.x, x4.x, a0); a1 = fmaf(w4.y, x4.y, a1);
            a2 = fmaf(w4.z, x4.z, a2); a3 = fmaf(w4.w, x4.w, a3);
        }
        float acc = (a0 + a1) + (a2 + a3);
        acc += __shfl_xor(acc, 1);
        acc += __shfl_xor(acc, 2);
        acc += __shfl_xor(acc, 4);
        acc += __shfl_xor(acc, 8);
        if (part == 0)
            kv[d] = acc + (half ? bv : bk)[r * 256 + h * D_ + d];
    }
    __syncthreads();

    // ---- fold (split over lane pair) + hi/lo split + fragment write ----
    {
        float x = 0.f;
        #pragma unroll
        for (int i = 0; i < 16; ++i)
            x = fmaf(kv[dh * 16 + i], fw[i], x);
        x += __shfl_xor(x, 1);         // combine d-halves

        if (half == 0) {
            // WLf tile (kt=c>>4, mt=rh>>5); lane=((c>>3)&1)*32+(rh&31); e=c&7
            const size_t off =
                ((size_t)((c >> 4) * 4 + (rh >> 5)) * 64
                 + ((c >> 3) & 1) * 32 + (rh & 31)) * 8 + (c & 7);
            const short hi = bf16rn(x);
            if (dh == 0) WLf_hi[off] = hi;
            else         WLf_lo[off] = bf16rn(x - bf16tof(hi));
        } else {
            x += 0.125f * bm[c];       // bm folded: sum_rh attn == NH_ == 8
            // Uf tile (kt=rh>>4, mt=c>>5); lane=((rh>>3)&1)*32+(c&31); e=rh&7
            const size_t off =
                ((size_t)((rh >> 4) * 8 + (c >> 5)) * 64
                 + ((rh >> 3) & 1) * 32 + (c & 31)) * 8 + (rh & 7);
            const short hi = bf16rn(x);
            if (dh == 0) Uf_hi[off] = hi;
            else         Uf_lo[off] = bf16rn(x - bf16tof(hi));
        }
    }

    // ---- c0[rh] = k · bq slice ----
    if (half == 0 && tid < D_) {
        float s = kv[tid] * bq[rh * D_ + tid];
        s += __shfl_xor(s, 1);  s += __shfl_xor(s, 2);  s += __shfl_xor(s, 4);
        s += __shfl_xor(s, 8);  s += __shfl_xor(s, 16);
        if (tid == 0) c0o[rh] = s;
    }
}

// ---------------------------------------------------------------------------
// MFMA main: 512 blocks x 512 thr (8 waves), 32 positions per block.
// R19 = R16 (the 22.1us best: dual accumulators, P0+P1, launch_bounds(512,4))
// with ONE fix: the softmax/scatter bank conflict.
//   * softmax thread map (h=tid&7, p=tid>>3) + PST=36:
//       - P0/P1 reads:  bank=(4h+p)%32      -> exactly 2-way (free, m136)
//       - Bf scatter:   bank=4(p&7)+(h>>1)  -> 32 banks x 2 lanes (free)
//     (R16's map (h=tid>>5,p=tid&31) gave bank=(p&7)*4 -> 8-way, 393K
//      conflicts measured in R17's counter run.)
//   Phase 0: z B-frags -> Bf; prefetch GEMM1 kt0 A-frags
//   Phase 1: GEMM1 split-K (mt=w&3, ks=w>>2) -> P0 (+c0) / P1
//   Phase 2 (fused): softmax + direct attn-fragment scatter into Bf;
//            prefetch GEMM2 kt0 A-frags
//   Phase 3: GEMM2 (mt=w, K=128) + store
// LDS = 32 + 2*18 = 68 KB -> 2 blocks/CU.
// C/D map (verified m74/m101): row=(r&3)+8(r>>2)+4g.
// ---------------------------------------------------------------------------
__global__ __launch_bounds__(512, 4)
void rims_mfma(const float* __restrict__ z,
               const short* __restrict__ WLf_hi, const short* __restrict__ WLf_lo,
               const short* __restrict__ Uf_hi,  const short* __restrict__ Uf_lo,
               const float* __restrict__ c0v,
               float* __restrict__ out)
{
    __shared__ short8 Bf[32 * 64];       // 32 KB
    __shared__ float  P0[RH_ * PST];     // 18 KB
    __shared__ float  P1[RH_ * PST];     // 18 KB

    const int tid = threadIdx.x;
    const int l   = tid & 63;
    const int w   = tid >> 6;            // 0..7
    const int g   = l >> 5;
    const int n31 = l & 31;
    const int b   = blockIdx.x >> 5;
    const int xy0 = (blockIdx.x & 31) * NT;
    const float* zb = z + (size_t)b * C_ * XY_ + xy0;

    const int mt1 = w & 3, ks = w >> 2;  // GEMM1 assignment
    const int kt0 = ks * 8;

    // ---- Phase 0: z B-frags (2 frag-pairs per wave) ----
    #pragma unroll
    for (int i = 0; i < 2; ++i) {
        const int kt = w * 2 + i;        // 0..15
        float x[8];
        short8 hi, lo;
        #pragma unroll
        for (int e = 0; e < 8; ++e)
            x[e] = zb[(size_t)(kt * 16 + 8 * g + e) * XY_ + n31];
        #pragma unroll
        for (int e = 0; e < 8; ++e) {
            const short hh = bf16rn(x[e]);
            hi[e] = hh;
            lo[e] = bf16rn(x[e] - bf16tof(hh));
        }
        Bf[(kt * 2 + 0) * 64 + l] = hi;
        Bf[(kt * 2 + 1) * 64 + l] = lo;
    }

    // prefetch first GEMM1 A-frag pair (global only -> legal before barrier)
    const short8 w0h = *reinterpret_cast<const short8*>(
        WLf_hi + ((size_t)(kt0 * 4 + mt1) * 64 + l) * 8);
    const short8 w0l = *reinterpret_cast<const short8*>(
        WLf_lo + ((size_t)(kt0 * 4 + mt1) * 64 + l) * 8);
    __syncthreads();

    // ---- Phase 1: GEMM1 split-K (M=128 rh, N=32, K=256) ----
    {
        f32x16 aA, aB;
        #pragma unroll
        for (int i = 0; i < 16; ++i) { aA[i] = 0.f; aB[i] = 0.f; }

        // peeled kt0 (A-frags already in registers)
        {
            const short8 bhi = Bf[(kt0 * 2 + 0) * 64 + l];
            const short8 blo = Bf[(kt0 * 2 + 1) * 64 + l];
            aA = __builtin_amdgcn_mfma_f32_32x32x16_bf16(w0h, bhi, aA, 0, 0, 0);
            aB = __builtin_amdgcn_mfma_f32_32x32x16_bf16(w0h, blo, aB, 0, 0, 0);
            aB = __builtin_amdgcn_mfma_f32_32x32x16_bf16(w0l, bhi, aB, 0, 0, 0);
        }
        #pragma unroll 2
        for (int k8 = 1; k8 < 8; ++k8) {
            const int kt = kt0 + k8;
            const short8 bhi = Bf[(kt * 2 + 0) * 64 + l];
            const short8 blo = Bf[(kt * 2 + 1) * 64 + l];
            const short8 ahi = *reinterpret_cast<const short8*>(
                WLf_hi + ((size_t)(kt * 4 + mt1) * 64 + l) * 8);
            const short8 alo = *reinterpret_cast<const short8*>(
                WLf_lo + ((size_t)(kt * 4 + mt1) * 64 + l) * 8);
            aA = __builtin_amdgcn_mfma_f32_32x32x16_bf16(ahi, bhi, aA, 0, 0, 0);
            aB = __builtin_amdgcn_mfma_f32_32x32x16_bf16(ahi, blo, aB, 0, 0, 0);
            aB = __builtin_amdgcn_mfma_f32_32x32x16_bf16(alo, bhi, aB, 0, 0, 0);
        }
        const f32x16 acc = aA + aB;
        if (ks == 0) {
            #pragma unroll
            for (int r = 0; r < 16; ++r) {
                const int row = (r & 3) + 8 * (r >> 2) + 4 * g;
                const int rg  = mt1 * 32 + row;
                P0[rg * PST + n31] = acc[r] + c0v[rg];   // c0 folded here
            }
        } else {
            #pragma unroll
            for (int r = 0; r < 16; ++r) {
                const int row = (r & 3) + 8 * (r >> 2) + 4 * g;
                P1[(mt1 * 32 + row) * PST + n31] = acc[r];
            }
        }
    }
    __syncthreads();

    // ---- Phase 2 (fused): softmax + direct attn-fragment scatter ----
    // thread map (h=tid&7, p=tid>>3): reads and scatter both ~2-way (free)
    if (tid < 256) {
        const int h = tid & 7;           // 0..7
        const int p = tid >> 3;          // 0..31
        float v[R_];
        float mx = -1e30f;
        #pragma unroll
        for (int r = 0; r < R_; ++r) {
            const int row = r * NH_ + h;
            v[r] = P0[row * PST + p] + P1[row * PST + p];
            mx = fmaxf(mx, v[r]);
        }
        float s = 0.f;
        #pragma unroll
        for (int r = 0; r < R_; ++r) { v[r] = __expf(v[r] - mx); s += v[r]; }
        const float inv = 1.f / s;

        short* bfs = reinterpret_cast<short*>(Bf);
        #pragma unroll
        for (int r = 0; r < R_; ++r) {
            const float a  = v[r] * inv;
            const short hi = bf16rn(a);
            const short lo = bf16rn(a - bf16tof(hi));
            const int kt   = r >> 1;
            const int lane = (r & 1) * 32 + p;
            bfs[((kt * 2 + 0) * 64 + lane) * 8 + h] = hi;
            bfs[((kt * 2 + 1) * 64 + lane) * 8 + h] = lo;
        }
    }

    // prefetch first GEMM2 A-frag pair (global only; overlaps softmax)
    const short8 u0h = *reinterpret_cast<const short8*>(
        Uf_hi + ((size_t)w * 64 + l) * 8);             // kt=0 -> idx = mt = w
    const short8 u0l = *reinterpret_cast<const short8*>(
        Uf_lo + ((size_t)w * 64 + l) * 8);
    __syncthreads();

    // ---- Phase 3: GEMM2 (M=256 c, N=32, K=128) + store ----
    {
        const int mt = w;                // c tile [32w, 32w+32)
        f32x16 p, q;
        #pragma unroll
        for (int i = 0; i < 16; ++i) { p[i] = 0.f; q[i] = 0.f; }

        // peeled kt=0
        {
            const short8 bhi = Bf[0 * 64 + l];
            const short8 blo = Bf[1 * 64 + l];
            p = __builtin_amdgcn_mfma_f32_32x32x16_bf16(u0h, bhi, p, 0, 0, 0);
            q = __builtin_amdgcn_mfma_f32_32x32x16_bf16(u0h, blo, q, 0, 0, 0);
            q = __builtin_amdgcn_mfma_f32_32x32x16_bf16(u0l, bhi, q, 0, 0, 0);
        }
        #pragma unroll 2
        for (int kt = 1; kt < 8; ++kt) {
            const short8 bhi = Bf[(kt * 2 + 0) * 64 + l];
            const short8 blo = Bf[(kt * 2 + 1) * 64 + l];
            const short8 ahi = *reinterpret_cast<const short8*>(
                Uf_hi + ((size_t)(kt * 8 + mt) * 64 + l) * 8);
            const short8 alo = *reinterpret_cast<const short8*>(
                Uf_lo + ((size_t)(kt * 8 + mt) * 64 + l) * 8);
            p = __builtin_amdgcn_mfma_f32_32x32x16_bf16(ahi, bhi, p, 0, 0, 0);
            q = __builtin_amdgcn_mfma_f32_32x32x16_bf16(ahi, blo, q, 0, 0, 0);
            q = __builtin_amdgcn_mfma_f32_32x32x16_bf16(alo, bhi, q, 0, 0, 0);
        }
        const f32x16 o = p + q;

        float* ob = out + (size_t)b * C_ * XY_ + xy0 + n31;
        #pragma unroll
        for (int r = 0; r < 16; ++r) {
            const int row = (r & 3) + 8 * (r >> 2) + 4 * g;
            ob[(size_t)(mt * 32 + row) * XY_] = o[r];
        }
    }
}

// ---------------------------------------------------------------------------
extern "C" void kernel_launch(void* const* d_in, const int* in_sizes, int n_in,
                              void* d_out, int out_size, void* d_ws, size_t ws_size,
                              hipStream_t stream)
{
    const float* z    = (const float*)d_in[0];
    const float* rims = (const float*)d_in[1];
    const float* Wk   = (const float*)d_in[2];
    const float* bk   = (const float*)d_in[3];
    const float* Wv   = (const float*)d_in[4];
    const float* bv   = (const float*)d_in[5];
    const float* Wq   = (const float*)d_in[6];
    const float* bq   = (const float*)d_in[7];
    const float* Wm   = (const float*)d_in[8];
    const float* bm   = (const float*)d_in[9];
    float* out = (float*)d_out;

    // ws: WLf_hi/lo (32768 shorts each) | Uf_hi/lo | c0 (256 f)
    short* WLf_hi = (short*)d_ws;
    short* WLf_lo = WLf_hi + 32768;
    short* Uf_hi  = WLf_lo + 32768;
    short* Uf_lo  = Uf_hi + 32768;
    float* c0o    = (float*)(Uf_lo + 32768);

    rims_precompute<<<2 * RH_, 512, 0, stream>>>(rims, Wk, bk, Wv, bv, Wq, bq,
                                                 Wm, bm, WLf_hi, WLf_lo,
                                                 Uf_hi, Uf_lo, c0o);
    rims_mfma<<<(B_ * XY_) / NT, 512, 0, stream>>>(z, WLf_hi, WLf_lo,
                                                   Uf_hi, Uf_lo, c0o, out);
}

// Round 20
// 20.727 us; speedup vs baseline: 7.6909x; 1.0499x over previous
//
#include <hip/hip_runtime.h>
#include <cstdint>
#include <cstddef>

// Dims (fixed by the reference)
#define R_   16
#define NH_  8
#define D_   32
#define C_   256
#define B_   16
#define XY_  1024      // 32*32
#define RH_  128       // R_*NH_
#define KD_  4096      // R_*NH_*D_
#define NT   32        // positions per block (main kernel)
#define PST  36        // partial LDS row stride (floats; bank math per R19)

#define LD4(p) (*reinterpret_cast<const float4*>(p))

using short8 = __attribute__((ext_vector_type(8))) short;   // 8 bf16 (4 VGPR)
using f32x16 = __attribute__((ext_vector_type(16))) float;  // MFMA 32x32 acc

__device__ __forceinline__ short bf16rn(float x) {
    unsigned u = __float_as_uint(x);
    u = (u + 0x7FFFu + ((u >> 16) & 1u)) >> 16;
    return (short)u;
}
__device__ __forceinline__ float bf16tof(short h) {
    return __uint_as_float(((unsigned)(unsigned short)h) << 16);
}

// ---------------------------------------------------------------------------
// Precompute + pack fused. 256 blocks (bid = rh*2 + half) x 512 thr.
// R20 delta: weights stored as SINGLE bf16 (hi only) — quantified error
// budget: GEMM1-path contribution ~5e-8 (suppressed by |U|), GEMM2-path
// <= 2^-9*|U|*sum(attn)=8 ~ 5.6e-6 worst. z / attn stay exact hi+lo.
// Fragment convention (32x32x16, A and B share it): lane l -> non-K = l&31,
// K-slot e -> k = kt*16 + 8*(l>>5) + e.
// ---------------------------------------------------------------------------
__global__ __launch_bounds__(512)
void rims_precompute(const float* __restrict__ rims,
                     const float* __restrict__ Wk,
                     const float* __restrict__ bk,
                     const float* __restrict__ Wv,
                     const float* __restrict__ bv,
                     const float* __restrict__ Wq,
                     const float* __restrict__ bq,
                     const float* __restrict__ Wm,
                     const float* __restrict__ bm,
                     short* __restrict__ WLf,
                     short* __restrict__ Uf,
                     float* __restrict__ c0o)
{
    const int bid  = blockIdx.x;       // 0..255
    const int rh   = bid >> 1;
    const int half = bid & 1;
    const int r    = rh >> 3;
    const int h    = rh & 7;
    const int tid  = threadIdx.x;      // 0..511
    const int c    = tid >> 1;         // 0..255
    const int dh   = tid & 1;          // d-half selector

    __shared__ float kv[D_];

    // ---- prefetch fold weights (latency overlaps dots) ----
    float fw[16];
    if (half == 0) {
        const float* wqp = Wq + ((size_t)rh * D_ + dh * 16) * C_ + c;
        #pragma unroll
        for (int i = 0; i < 16; ++i)
            fw[i] = wqp[(size_t)i * C_];
    } else {
        const float* wmp = Wm + (size_t)c * KD_ + rh * D_ + dh * 16;
        #pragma unroll
        for (int i4 = 0; i4 < 16; i4 += 4) {
            const float4 m4 = LD4(wmp + i4);
            fw[i4 + 0] = m4.x; fw[i4 + 1] = m4.y;
            fw[i4 + 2] = m4.z; fw[i4 + 3] = m4.w;
        }
    }

    // ---- k/v dots: 32 dots x 16 lanes, line-coalesced ----
    {
        const int d    = tid >> 4;     // 0..31
        const int part = tid & 15;     // 0..15
        const float* Wsrc = (half ? Wv : Wk)
                          + ((size_t)r * 256 + h * D_ + d) * C_ + part * 4;
        const float* rr   = rims + r * C_ + part * 4;
        float a0 = 0.f, a1 = 0.f, a2 = 0.f, a3 = 0.f;
        #pragma unroll
        for (int j = 0; j < 4; ++j) {
            const float4 w4 = LD4(Wsrc + j * 64);
            const float4 x4 = LD4(rr + j * 64);
            a0 = fmaf(w4.x, x4.x, a0); a1 = fmaf(w4.y, x4.y, a1);
            a2 = fmaf(w4.z, x4.z, a2); a3 = fmaf(w4.w, x4.w, a3);
        }
        float acc = (a0 + a1) + (a2 + a3);
        acc += __shfl_xor(acc, 1);
        acc += __shfl_xor(acc, 2);
        acc += __shfl_xor(acc, 4);
        acc += __shfl_xor(acc, 8);
        if (part == 0)
            kv[d] = acc + (half ? bv : bk)[r * 256 + h * D_ + d];
    }
    __syncthreads();

    // ---- fold (split over lane pair) + single-bf16 fragment write ----
    {
        float x = 0.f;
        #pragma unroll
        for (int i = 0; i < 16; ++i)
            x = fmaf(kv[dh * 16 + i], fw[i], x);
        x += __shfl_xor(x, 1);         // combine d-halves

        if (dh == 0) {
            if (half == 0) {
                // WLf tile (kt=c>>4, mt=rh>>5); lane=((c>>3)&1)*32+(rh&31); e=c&7
                const size_t off =
                    ((size_t)((c >> 4) * 4 + (rh >> 5)) * 64
                     + ((c >> 3) & 1) * 32 + (rh & 31)) * 8 + (c & 7);
                WLf[off] = bf16rn(x);
            } else {
                x += 0.125f * bm[c];   // bm folded: sum_rh attn == NH_ == 8
                // Uf tile (kt=rh>>4, mt=c>>5); lane=((rh>>3)&1)*32+(c&31); e=rh&7
                const size_t off =
                    ((size_t)((rh >> 4) * 8 + (c >> 5)) * 64
                     + ((rh >> 3) & 1) * 32 + (c & 31)) * 8 + (rh & 7);
                Uf[off] = bf16rn(x);
            }
        }
    }

    // ---- c0[rh] = k · bq slice ----
    if (half == 0 && tid < D_) {
        float s = kv[tid] * bq[rh * D_ + tid];
        s += __shfl_xor(s, 1);  s += __shfl_xor(s, 2);  s += __shfl_xor(s, 4);
        s += __shfl_xor(s, 8);  s += __shfl_xor(s, 16);
        if (tid == 0) c0o[rh] = s;
    }
}

// ---------------------------------------------------------------------------
// MFMA main: 512 blocks x 512 thr (8 waves), 32 positions per block.
// R20 = R19 with single-bf16 weights: 2 MFMAs per kt (W*b_hi, W*b_lo) in
// both GEMMs (dual independent accumulator chains kept — R18 lesson),
// halved A-frag VMEM traffic (64 MB L2 total).
//   Phase 0: z B-frags (exact hi/lo) -> Bf; prefetch GEMM1 kt0 A-frag
//   Phase 1: GEMM1 split-K (mt=w&3, ks=w>>2) -> P0 (+c0) / P1
//   Phase 2 (fused): softmax + direct attn-fragment scatter into Bf
//            (map h=tid&7, p=tid>>3: reads & scatter ~2-way, free);
//            prefetch GEMM2 kt0 A-frag
//   Phase 3: GEMM2 (mt=w, K=128) + store
// LDS = 32 + 2*18 = 68 KB -> 2 blocks/CU.
// C/D map (verified m74/m101): row=(r&3)+8(r>>2)+4g.
// ---------------------------------------------------------------------------
__global__ __launch_bounds__(512, 4)
void rims_mfma(const float* __restrict__ z,
               const short* __restrict__ WLf,
               const short* __restrict__ Uf,
               const float* __restrict__ c0v,
               float* __restrict__ out)
{
    __shared__ short8 Bf[32 * 64];       // 32 KB
    __shared__ float  P0[RH_ * PST];     // 18 KB
    __shared__ float  P1[RH_ * PST];     // 18 KB

    const int tid = threadIdx.x;
    const int l   = tid & 63;
    const int w   = tid >> 6;            // 0..7
    const int g   = l >> 5;
    const int n31 = l & 31;
    const int b   = blockIdx.x >> 5;
    const int xy0 = (blockIdx.x & 31) * NT;
    const float* zb = z + (size_t)b * C_ * XY_ + xy0;

    const int mt1 = w & 3, ks = w >> 2;  // GEMM1 assignment
    const int kt0 = ks * 8;

    // ---- Phase 0: z B-frags (2 frag-pairs per wave) ----
    #pragma unroll
    for (int i = 0; i < 2; ++i) {
        const int kt = w * 2 + i;        // 0..15
        float x[8];
        short8 hi, lo;
        #pragma unroll
        for (int e = 0; e < 8; ++e)
            x[e] = zb[(size_t)(kt * 16 + 8 * g + e) * XY_ + n31];
        #pragma unroll
        for (int e = 0; e < 8; ++e) {
            const short hh = bf16rn(x[e]);
            hi[e] = hh;
            lo[e] = bf16rn(x[e] - bf16tof(hh));
        }
        Bf[(kt * 2 + 0) * 64 + l] = hi;
        Bf[(kt * 2 + 1) * 64 + l] = lo;
    }

    // prefetch first GEMM1 A-frag (global only -> legal before barrier)
    const short8 w0 = *reinterpret_cast<const short8*>(
        WLf + ((size_t)(kt0 * 4 + mt1) * 64 + l) * 8);
    __syncthreads();

    // ---- Phase 1: GEMM1 split-K (M=128 rh, N=32, K=256) ----
    {
        f32x16 aA, aB;
        #pragma unroll
        for (int i = 0; i < 16; ++i) { aA[i] = 0.f; aB[i] = 0.f; }

        // peeled kt0 (A-frag already in registers)
        {
            const short8 bhi = Bf[(kt0 * 2 + 0) * 64 + l];
            const short8 blo = Bf[(kt0 * 2 + 1) * 64 + l];
            aA = __builtin_amdgcn_mfma_f32_32x32x16_bf16(w0, bhi, aA, 0, 0, 0);
            aB = __builtin_amdgcn_mfma_f32_32x32x16_bf16(w0, blo, aB, 0, 0, 0);
        }
        #pragma unroll 2
        for (int k8 = 1; k8 < 8; ++k8) {
            const int kt = kt0 + k8;
            const short8 bhi = Bf[(kt * 2 + 0) * 64 + l];
            const short8 blo = Bf[(kt * 2 + 1) * 64 + l];
            const short8 a = *reinterpret_cast<const short8*>(
                WLf + ((size_t)(kt * 4 + mt1) * 64 + l) * 8);
            aA = __builtin_amdgcn_mfma_f32_32x32x16_bf16(a, bhi, aA, 0, 0, 0);
            aB = __builtin_amdgcn_mfma_f32_32x32x16_bf16(a, blo, aB, 0, 0, 0);
        }
        const f32x16 acc = aA + aB;
        if (ks == 0) {
            #pragma unroll
            for (int r = 0; r < 16; ++r) {
                const int row = (r & 3) + 8 * (r >> 2) + 4 * g;
                const int rg  = mt1 * 32 + row;
                P0[rg * PST + n31] = acc[r] + c0v[rg];   // c0 folded here
            }
        } else {
            #pragma unroll
            for (int r = 0; r < 16; ++r) {
                const int row = (r & 3) + 8 * (r >> 2) + 4 * g;
                P1[(mt1 * 32 + row) * PST + n31] = acc[r];
            }
        }
    }
    __syncthreads();

    // ---- Phase 2 (fused): softmax + direct attn-fragment scatter ----
    // thread map (h=tid&7, p=tid>>3): reads and scatter both ~2-way (free)
    if (tid < 256) {
        const int h = tid & 7;           // 0..7
        const int p = tid >> 3;          // 0..31
        float v[R_];
        float mx = -1e30f;
        #pragma unroll
        for (int r = 0; r < R_; ++r) {
            const int row = r * NH_ + h;
            v[r] = P0[row * PST + p] + P1[row * PST + p];
            mx = fmaxf(mx, v[r]);
        }
        float s = 0.f;
        #pragma unroll
        for (int r = 0; r < R_; ++r) { v[r] = __expf(v[r] - mx); s += v[r]; }
        const float inv = 1.f / s;

        short* bfs = reinterpret_cast<short*>(Bf);
        #pragma unroll
        for (int r = 0; r < R_; ++r) {
            const float a  = v[r] * inv;
            const short hi = bf16rn(a);
            const short lo = bf16rn(a - bf16tof(hi));
            const int kt   = r >> 1;
            const int lane = (r & 1) * 32 + p;
            bfs[((kt * 2 + 0) * 64 + lane) * 8 + h] = hi;
            bfs[((kt * 2 + 1) * 64 + lane) * 8 + h] = lo;
        }
    }

    // prefetch first GEMM2 A-frag (global only; overlaps softmax)
    const short8 u0 = *reinterpret_cast<const short8*>(
        Uf + ((size_t)w * 64 + l) * 8);                // kt=0 -> idx = mt = w
    __syncthreads();

    // ---- Phase 3: GEMM2 (M=256 c, N=32, K=128) + store ----
    {
        const int mt = w;                // c tile [32w, 32w+32)
        f32x16 p, q;
        #pragma unroll
        for (int i = 0; i < 16; ++i) { p[i] = 0.f; q[i] = 0.f; }

        // peeled kt=0
        {
            const short8 bhi = Bf[0 * 64 + l];
            const short8 blo = Bf[1 * 64 + l];
            p = __builtin_amdgcn_mfma_f32_32x32x16_bf16(u0, bhi, p, 0, 0, 0);
            q = __builtin_amdgcn_mfma_f32_32x32x16_bf16(u0, blo, q, 0, 0, 0);
        }
        #pragma unroll 2
        for (int kt = 1; kt < 8; ++kt) {
            const short8 bhi = Bf[(kt * 2 + 0) * 64 + l];
            const short8 blo = Bf[(kt * 2 + 1) * 64 + l];
            const short8 a = *reinterpret_cast<const short8*>(
                Uf + ((size_t)(kt * 8 + mt) * 64 + l) * 8);
            p = __builtin_amdgcn_mfma_f32_32x32x16_bf16(a, bhi, p, 0, 0, 0);
            q = __builtin_amdgcn_mfma_f32_32x32x16_bf16(a, blo, q, 0, 0, 0);
        }
        const f32x16 o = p + q;

        float* ob = out + (size_t)b * C_ * XY_ + xy0 + n31;
        #pragma unroll
        for (int r = 0; r < 16; ++r) {
            const int row = (r & 3) + 8 * (r >> 2) + 4 * g;
            ob[(size_t)(mt * 32 + row) * XY_] = o[r];
        }
    }
}

// ---------------------------------------------------------------------------
extern "C" void kernel_launch(void* const* d_in, const int* in_sizes, int n_in,
                              void* d_out, int out_size, void* d_ws, size_t ws_size,
                              hipStream_t stream)
{
    const float* z    = (const float*)d_in[0];
    const float* rims = (const float*)d_in[1];
    const float* Wk   = (const float*)d_in[2];
    const float* bk   = (const float*)d_in[3];
    const float* Wv   = (const float*)d_in[4];
    const float* bv   = (const float*)d_in[5];
    const float* Wq   = (const float*)d_in[6];
    const float* bq   = (const float*)d_in[7];
    const float* Wm   = (const float*)d_in[8];
    const float* bm   = (const float*)d_in[9];
    float* out = (float*)d_out;

    // ws: WLf (32768 shorts) | Uf (32768 shorts) | c0 (256 f)
    short* WLf = (short*)d_ws;
    short* Uf  = WLf + 32768;
    float* c0o = (float*)(Uf + 32768);

    rims_precompute<<<2 * RH_, 512, 0, stream>>>(rims, Wk, bk, Wv, bv, Wq, bq,
                                                 Wm, bm, WLf, Uf, c0o);
    rims_mfma<<<(B_ * XY_) / NT, 512, 0, stream>>>(z, WLf, Uf, c0o, out);
}

// Round 21
// 20.229 us; speedup vs baseline: 7.8801x; 1.0246x over previous
//
#include <hip/hip_runtime.h>
#include <cstdint>
#include <cstddef>

// Dims (fixed by the reference)
#define R_   16
#define NH_  8
#define D_   32
#define C_   256
#define B_   16
#define XY_  1024      // 32*32
#define RH_  128       // R_*NH_
#define KD_  4096      // R_*NH_*D_
#define NT   32        // positions per block (main kernel)
#define PST  36        // partial LDS row stride (floats; bank math per R19)

#define LD4(p) (*reinterpret_cast<const float4*>(p))

using short8 = __attribute__((ext_vector_type(8))) short;   // 8 bf16 (4 VGPR)
using f32x16 = __attribute__((ext_vector_type(16))) float;  // MFMA 32x32 acc

__device__ __forceinline__ short bf16rn(float x) {
    unsigned u = __float_as_uint(x);
    u = (u + 0x7FFFu + ((u >> 16) & 1u)) >> 16;
    return (short)u;
}
__device__ __forceinline__ float bf16tof(short h) {
    return __uint_as_float(((unsigned)(unsigned short)h) << 16);
}

// ---------------------------------------------------------------------------
// Precompute + pack fused (identical to R20). 256 blocks x 512 thr.
// Weights stored as SINGLE bf16 (hi only) — error budget ~5e-6 worst case,
// verified R20: absmax unchanged at 3.8e-6. z / attn stay exact hi+lo.
// Fragment convention (32x32x16, A and B share it): lane l -> non-K = l&31,
// K-slot e -> k = kt*16 + 8*(l>>5) + e.
// ---------------------------------------------------------------------------
__global__ __launch_bounds__(512)
void rims_precompute(const float* __restrict__ rims,
                     const float* __restrict__ Wk,
                     const float* __restrict__ bk,
                     const float* __restrict__ Wv,
                     const float* __restrict__ bv,
                     const float* __restrict__ Wq,
                     const float* __restrict__ bq,
                     const float* __restrict__ Wm,
                     const float* __restrict__ bm,
                     short* __restrict__ WLf,
                     short* __restrict__ Uf,
                     float* __restrict__ c0o)
{
    const int bid  = blockIdx.x;       // 0..255
    const int rh   = bid >> 1;
    const int half = bid & 1;
    const int r    = rh >> 3;
    const int h    = rh & 7;
    const int tid  = threadIdx.x;      // 0..511
    const int c    = tid >> 1;         // 0..255
    const int dh   = tid & 1;          // d-half selector

    __shared__ float kv[D_];

    // ---- prefetch fold weights (latency overlaps dots) ----
    float fw[16];
    if (half == 0) {
        const float* wqp = Wq + ((size_t)rh * D_ + dh * 16) * C_ + c;
        #pragma unroll
        for (int i = 0; i < 16; ++i)
            fw[i] = wqp[(size_t)i * C_];
    } else {
        const float* wmp = Wm + (size_t)c * KD_ + rh * D_ + dh * 16;
        #pragma unroll
        for (int i4 = 0; i4 < 16; i4 += 4) {
            const float4 m4 = LD4(wmp + i4);
            fw[i4 + 0] = m4.x; fw[i4 + 1] = m4.y;
            fw[i4 + 2] = m4.z; fw[i4 + 3] = m4.w;
        }
    }

    // ---- k/v dots: 32 dots x 16 lanes, line-coalesced ----
    {
        const int d    = tid >> 4;     // 0..31
        const int part = tid & 15;     // 0..15
        const float* Wsrc = (half ? Wv : Wk)
                          + ((size_t)r * 256 + h * D_ + d) * C_ + part * 4;
        const float* rr   = rims + r * C_ + part * 4;
        float a0 = 0.f, a1 = 0.f, a2 = 0.f, a3 = 0.f;
        #pragma unroll
        for (int j = 0; j < 4; ++j) {
            const float4 w4 = LD4(Wsrc + j * 64);
            const float4 x4 = LD4(rr + j * 64);
            a0 = fmaf(w4.x, x4.x, a0); a1 = fmaf(w4.y, x4.y, a1);
            a2 = fmaf(w4.z, x4.z, a2); a3 = fmaf(w4.w, x4.w, a3);
        }
        float acc = (a0 + a1) + (a2 + a3);
        acc += __shfl_xor(acc, 1);
        acc += __shfl_xor(acc, 2);
        acc += __shfl_xor(acc, 4);
        acc += __shfl_xor(acc, 8);
        if (part == 0)
            kv[d] = acc + (half ? bv : bk)[r * 256 + h * D_ + d];
    }
    __syncthreads();

    // ---- fold (split over lane pair) + single-bf16 fragment write ----
    {
        float x = 0.f;
        #pragma unroll
        for (int i = 0; i < 16; ++i)
            x = fmaf(kv[dh * 16 + i], fw[i], x);
        x += __shfl_xor(x, 1);         // combine d-halves

        if (dh == 0) {
            if (half == 0) {
                // WLf tile (kt=c>>4, mt=rh>>5); lane=((c>>3)&1)*32+(rh&31); e=c&7
                const size_t off =
                    ((size_t)((c >> 4) * 4 + (rh >> 5)) * 64
                     + ((c >> 3) & 1) * 32 + (rh & 31)) * 8 + (c & 7);
                WLf[off] = bf16rn(x);
            } else {
                x += 0.125f * bm[c];   // bm folded: sum_rh attn == NH_ == 8
                // Uf tile (kt=rh>>4, mt=c>>5); lane=((rh>>3)&1)*32+(c&31); e=rh&7
                const size_t off =
                    ((size_t)((rh >> 4) * 8 + (c >> 5)) * 64
                     + ((rh >> 3) & 1) * 32 + (c & 31)) * 8 + (rh & 7);
                Uf[off] = bf16rn(x);
            }
        }
    }

    // ---- c0[rh] = k · bq slice ----
    if (half == 0 && tid < D_) {
        float s = kv[tid] * bq[rh * D_ + tid];
        s += __shfl_xor(s, 1);  s += __shfl_xor(s, 2);  s += __shfl_xor(s, 4);
        s += __shfl_xor(s, 8);  s += __shfl_xor(s, 16);
        if (tid == 0) c0o[rh] = s;
    }
}

// ---------------------------------------------------------------------------
// MFMA main: 512 blocks x 512 thr (8 waves), 32 positions per block.
// R21 = R20 + FULL cross-barrier A-frag register prefetch:
//   * all 8 phase-1 WLf frags issued in phase 0 (global-only reads; in-order
//     VMEM returns hide under z-conversion VALU + barrier)
//   * all 8 phase-3 Uf frags issued right after phase-1 P-writes (hide under
//     barrier + softmax + barrier)
//   Static-index unrolled arrays (rule #20 safe); +32 VGPR per phase with
//   non-overlapping live ranges.
//   Phase 0: z B-frags -> Bf; prefetch wA[0..7]
//   Phase 1: GEMM1 split-K (mt=w&3, ks=w>>2) -> P0 (+c0) / P1; prefetch uA
//   Phase 2 (fused): softmax + direct attn-fragment scatter into Bf
//            (map h=tid&7, p=tid>>3: reads & scatter ~2-way, free)
//   Phase 3: GEMM2 (mt=w, K=128) + store
// LDS = 32 + 2*18 = 68 KB -> 2 blocks/CU.
// C/D map (verified m74/m101): row=(r&3)+8(r>>2)+4g.
// ---------------------------------------------------------------------------
__global__ __launch_bounds__(512, 4)
void rims_mfma(const float* __restrict__ z,
               const short* __restrict__ WLf,
               const short* __restrict__ Uf,
               const float* __restrict__ c0v,
               float* __restrict__ out)
{
    __shared__ short8 Bf[32 * 64];       // 32 KB
    __shared__ float  P0[RH_ * PST];     // 18 KB
    __shared__ float  P1[RH_ * PST];     // 18 KB

    const int tid = threadIdx.x;
    const int l   = tid & 63;
    const int w   = tid >> 6;            // 0..7
    const int g   = l >> 5;
    const int n31 = l & 31;
    const int b   = blockIdx.x >> 5;
    const int xy0 = (blockIdx.x & 31) * NT;
    const float* zb = z + (size_t)b * C_ * XY_ + xy0;

    const int mt1 = w & 3, ks = w >> 2;  // GEMM1 assignment
    const int kt0 = ks * 8;

    // ---- Phase 0: z B-frags (2 frag-pairs per wave) ----
    #pragma unroll
    for (int i = 0; i < 2; ++i) {
        const int kt = w * 2 + i;        // 0..15
        float x[8];
        short8 hi, lo;
        #pragma unroll
        for (int e = 0; e < 8; ++e)
            x[e] = zb[(size_t)(kt * 16 + 8 * g + e) * XY_ + n31];
        #pragma unroll
        for (int e = 0; e < 8; ++e) {
            const short hh = bf16rn(x[e]);
            hi[e] = hh;
            lo[e] = bf16rn(x[e] - bf16tof(hh));
        }
        Bf[(kt * 2 + 0) * 64 + l] = hi;
        Bf[(kt * 2 + 1) * 64 + l] = lo;
    }

    // prefetch ALL 8 GEMM1 A-frags (global-only; hide under conv + barrier)
    short8 wA[8];
    #pragma unroll
    for (int k8 = 0; k8 < 8; ++k8)
        wA[k8] = *reinterpret_cast<const short8*>(
            WLf + ((size_t)((kt0 + k8) * 4 + mt1) * 64 + l) * 8);
    __syncthreads();

    // ---- Phase 1: GEMM1 split-K (M=128 rh, N=32, K=256) ----
    {
        f32x16 aA, aB;
        #pragma unroll
        for (int i = 0; i < 16; ++i) { aA[i] = 0.f; aB[i] = 0.f; }

        #pragma unroll
        for (int k8 = 0; k8 < 8; ++k8) {
            const int kt = kt0 + k8;
            const short8 bhi = Bf[(kt * 2 + 0) * 64 + l];
            const short8 blo = Bf[(kt * 2 + 1) * 64 + l];
            aA = __builtin_amdgcn_mfma_f32_32x32x16_bf16(wA[k8], bhi, aA, 0, 0, 0);
            aB = __builtin_amdgcn_mfma_f32_32x32x16_bf16(wA[k8], blo, aB, 0, 0, 0);
        }
        const f32x16 acc = aA + aB;
        if (ks == 0) {
            #pragma unroll
            for (int r = 0; r < 16; ++r) {
                const int row = (r & 3) + 8 * (r >> 2) + 4 * g;
                const int rg  = mt1 * 32 + row;
                P0[rg * PST + n31] = acc[r] + c0v[rg];   // c0 folded here
            }
        } else {
            #pragma unroll
            for (int r = 0; r < 16; ++r) {
                const int row = (r & 3) + 8 * (r >> 2) + 4 * g;
                P1[(mt1 * 32 + row) * PST + n31] = acc[r];
            }
        }
    }

    // prefetch ALL 8 GEMM2 A-frags (hide under barrier + softmax + barrier)
    short8 uA[8];
    #pragma unroll
    for (int kt = 0; kt < 8; ++kt)
        uA[kt] = *reinterpret_cast<const short8*>(
            Uf + ((size_t)(kt * 8 + w) * 64 + l) * 8);
    __syncthreads();

    // ---- Phase 2 (fused): softmax + direct attn-fragment scatter ----
    // thread map (h=tid&7, p=tid>>3): reads and scatter both ~2-way (free)
    if (tid < 256) {
        const int h = tid & 7;           // 0..7
        const int p = tid >> 3;          // 0..31
        float v[R_];
        float mx = -1e30f;
        #pragma unroll
        for (int r = 0; r < R_; ++r) {
            const int row = r * NH_ + h;
            v[r] = P0[row * PST + p] + P1[row * PST + p];
            mx = fmaxf(mx, v[r]);
        }
        float s = 0.f;
        #pragma unroll
        for (int r = 0; r < R_; ++r) { v[r] = __expf(v[r] - mx); s += v[r]; }
        const float inv = 1.f / s;

        short* bfs = reinterpret_cast<short*>(Bf);
        #pragma unroll
        for (int r = 0; r < R_; ++r) {
            const float a  = v[r] * inv;
            const short hi = bf16rn(a);
            const short lo = bf16rn(a - bf16tof(hi));
            const int kt   = r >> 1;
            const int lane = (r & 1) * 32 + p;
            bfs[((kt * 2 + 0) * 64 + lane) * 8 + h] = hi;
            bfs[((kt * 2 + 1) * 64 + lane) * 8 + h] = lo;
        }
    }
    __syncthreads();

    // ---- Phase 3: GEMM2 (M=256 c, N=32, K=128) + store ----
    {
        const int mt = w;                // c tile [32w, 32w+32)
        f32x16 p, q;
        #pragma unroll
        for (int i = 0; i < 16; ++i) { p[i] = 0.f; q[i] = 0.f; }

        #pragma unroll
        for (int kt = 0; kt < 8; ++kt) {
            const short8 bhi = Bf[(kt * 2 + 0) * 64 + l];
            const short8 blo = Bf[(kt * 2 + 1) * 64 + l];
            p = __builtin_amdgcn_mfma_f32_32x32x16_bf16(uA[kt], bhi, p, 0, 0, 0);
            q = __builtin_amdgcn_mfma_f32_32x32x16_bf16(uA[kt], blo, q, 0, 0, 0);
        }
        const f32x16 o = p + q;

        float* ob = out + (size_t)b * C_ * XY_ + xy0 + n31;
        #pragma unroll
        for (int r = 0; r < 16; ++r) {
            const int row = (r & 3) + 8 * (r >> 2) + 4 * g;
            ob[(size_t)(mt * 32 + row) * XY_] = o[r];
        }
    }
}

// ---------------------------------------------------------------------------
extern "C" void kernel_launch(void* const* d_in, const int* in_sizes, int n_in,
                              void* d_out, int out_size, void* d_ws, size_t ws_size,
                              hipStream_t stream)
{
    const float* z    = (const float*)d_in[0];
    const float* rims = (const float*)d_in[1];
    const float* Wk   = (const float*)d_in[2];
    const float* bk   = (const float*)d_in[3];
    const float* Wv   = (const float*)d_in[4];
    const float* bv   = (const float*)d_in[5];
    const float* Wq   = (const float*)d_in[6];
    const float* bq   = (const float*)d_in[7];
    const float* Wm   = (const float*)d_in[8];
    const float* bm   = (const float*)d_in[9];
    float* out = (float*)d_out;

    // ws: WLf (32768 shorts) | Uf (32768 shorts) | c0 (256 f)
    short* WLf = (short*)d_ws;
    short* Uf  = WLf + 32768;
    float* c0o = (float*)(Uf + 32768);

    rims_precompute<<<2 * RH_, 512, 0, stream>>>(rims, Wk, bk, Wv, bv, Wq, bq,
                                                 Wm, bm, WLf, Uf, c0o);
    rims_mfma<<<(B_ * XY_) / NT, 512, 0, stream>>>(z, WLf, Uf, c0o, out);
}